// Round 1
// baseline (35.886 us; speedup 1.0000x reference)
//
#include <hip/hip_runtime.h>

// Tree positional embedding, closed form:
// out[i][8*j + child_idx(ancestor_j(i))] = 1.0 for j < min(depth[i], K), else 0.
// BRANCH=8, K_DEPTH=16 fixed by the harness; h = 128 floats/row.
// One thread per float4 chunk (32 chunks/row) -> fully coalesced stores.

#define PE_K 16

__global__ __launch_bounds__(256) void PositionalEmbedding_kernel(
    const int* __restrict__ parent,
    const int* __restrict__ child_idx,
    const int* __restrict__ depth,
    float* __restrict__ out,
    int N) {
  long long gid = (long long)blockIdx.x * blockDim.x + threadIdx.x;
  int row = (int)(gid >> 5);
  if (row >= N) return;
  int c = (int)(gid & 31);   // float4-chunk index within the 128-float row
  int j = c >> 1;            // which ancestor slot (8 floats = 2 chunks per slot)

  float4 v = make_float4(0.f, 0.f, 0.f, 0.f);

  int d = depth[row];
  int dd = d < PE_K ? d : PE_K;
  if (j < dd) {
    int cur = row;
    // walk up j parent links (j <= 5 for this forest since max depth = 6)
    for (int s = 0; s < j; ++s) cur = parent[cur];
    int ci = child_idx[cur];       // 0..7
    int hot = 8 * j + ci;          // global column holding the 1.0
    int base = c * 4;              // first column of this chunk
    v.x = (hot == base + 0) ? 1.f : 0.f;
    v.y = (hot == base + 1) ? 1.f : 0.f;
    v.z = (hot == base + 2) ? 1.f : 0.f;
    v.w = (hot == base + 3) ? 1.f : 0.f;
  }

  reinterpret_cast<float4*>(out)[(long long)row * 32 + c] = v;
}

extern "C" void kernel_launch(void* const* d_in, const int* in_sizes, int n_in,
                              void* d_out, int out_size, void* d_ws, size_t ws_size,
                              hipStream_t stream) {
  const int* parent    = (const int*)d_in[0];
  const int* child_idx = (const int*)d_in[1];
  const int* depth     = (const int*)d_in[2];
  // d_in[3] = p_emb (unused by the forward), d_in[4] = n (=8), d_in[5] = k (=16)
  float* out = (float*)d_out;
  int N = in_sizes[0];

  long long total = (long long)N * 32;           // one thread per float4
  int block = 256;
  int grid = (int)((total + block - 1) / block); // 25,000 blocks at N=200k
  PositionalEmbedding_kernel<<<grid, block, 0, stream>>>(parent, child_idx, depth, out, N);
}

// Round 2
// 22.233 us; speedup vs baseline: 1.6141x; 1.6141x over previous
//
#include <hip/hip_runtime.h>

// Tree positional embedding, closed form:
//   out[i][8*j + child_idx(ancestor_j(i))] = 1.0 for j < min(depth[i], K), else 0
// BRANCH=8, K_DEPTH=16 (h = 128 floats/row).
//
// Two-phase block design (64 rows/block, 256 threads):
//   Phase 1: wave 0, one lane per row, walks the parent chain once and packs
//            the row's hot-column code (3 bits per level, 16 levels) + clamped
//            depth into a 64-bit word in LDS. Loads are coalesced across lanes.
//   Phase 2: all 256 threads emit the 64x128 float tile as 2048 float4 stores,
//            fully coalesced, reading only the LDS codes (broadcast).
// This amortizes the dependent-load latency chain over 32 KiB of stores.

#define PE_K 16
#define ROWS_PER_BLOCK 64

__global__ __launch_bounds__(256) void PositionalEmbedding_kernel(
    const int* __restrict__ parent,
    const int* __restrict__ child_idx,
    const int* __restrict__ depth,
    float* __restrict__ out,
    int N) {
  __shared__ unsigned long long codes[ROWS_PER_BLOCK];

  const int tid  = threadIdx.x;
  const int row0 = blockIdx.x * ROWS_PER_BLOCK;

  // ---- Phase 1: one lane per row builds the packed ancestor code ----
  if (tid < ROWS_PER_BLOCK) {
    int row = row0 + tid;
    unsigned long long code = 0;
    if (row < N) {
      int d  = depth[row];
      int dd = d < PE_K ? d : PE_K;
      int cur = row;
      for (int j = 0; j < dd; ++j) {
        int ci = child_idx[cur] & 7;
        code |= (unsigned long long)ci << (3 * j);
        cur = parent[cur];
      }
      code |= (unsigned long long)dd << 48;
    }
    codes[tid] = code;
  }
  __syncthreads();

  // ---- Phase 2: stream the 64x32-float4 tile out, coalesced ----
  #pragma unroll
  for (int it = 0; it < (ROWS_PER_BLOCK * 32) / 256; ++it) {
    int idx = it * 256 + tid;          // 0..2047 chunk index within tile
    int rl  = idx >> 5;                // local row
    int c   = idx & 31;                // float4 chunk within row
    int row = row0 + rl;
    if (row >= N) continue;

    unsigned long long code = codes[rl];
    int dd = (int)(code >> 48);
    int j  = c >> 1;                   // 8-wide level slot (2 chunks per slot)

    float4 v = make_float4(0.f, 0.f, 0.f, 0.f);
    if (j < dd) {
      int ci   = (int)((code >> (3 * j)) & 7);
      int hot  = 8 * j + ci;
      int base = c * 4;
      v.x = (hot == base + 0) ? 1.f : 0.f;
      v.y = (hot == base + 1) ? 1.f : 0.f;
      v.z = (hot == base + 2) ? 1.f : 0.f;
      v.w = (hot == base + 3) ? 1.f : 0.f;
    }
    reinterpret_cast<float4*>(out)[(long long)row * 32 + c] = v;
  }
}

extern "C" void kernel_launch(void* const* d_in, const int* in_sizes, int n_in,
                              void* d_out, int out_size, void* d_ws, size_t ws_size,
                              hipStream_t stream) {
  const int* parent    = (const int*)d_in[0];
  const int* child_idx = (const int*)d_in[1];
  const int* depth     = (const int*)d_in[2];
  // d_in[3] = p_emb (unused), d_in[4] = n (=8), d_in[5] = k (=16)
  float* out = (float*)d_out;
  int N = in_sizes[0];

  int grid = (N + ROWS_PER_BLOCK - 1) / ROWS_PER_BLOCK;   // 3125 @ N=200k
  PositionalEmbedding_kernel<<<grid, 256, 0, stream>>>(parent, child_idx, depth, out, N);
}

// Round 3
// 21.623 us; speedup vs baseline: 1.6596x; 1.0282x over previous
//
#include <hip/hip_runtime.h>

// Tree positional embedding, closed form:
//   out[i][8*j + child_idx(ancestor_j(i))] = 1.0 for j < min(depth[i], K), else 0
// BRANCH=8, K_DEPTH=16 (h = 128 floats/row).
//
// Block = 256 threads, 128 rows (64 KB of output).
//   Phase 1: threads 0..127 each walk one row's parent chain, pack hot columns
//            (3 bits/level) + clamped depth into a u64 code in LDS.
//   Phase 2: per-thread constants: c = tid&31 (float4 chunk), j = c>>1 (slot),
//            shift = 3j, window base r0 = 4c-8j in {0,4}. Each of 16 unrolled
//            iterations: read code, extract child index (or 8 if j>=depth),
//            4 compares -> float4, one coalesced dwordx4 store. ~12 VALU/store.
// Grid = 1563 blocks -> fully resident on 256 CUs; walks overlap streaming.

#define PE_K 16
#define ROWS_PER_BLOCK 128

__global__ __launch_bounds__(256) void PositionalEmbedding_kernel(
    const int* __restrict__ parent,
    const int* __restrict__ child_idx,
    const int* __restrict__ depth,
    float* __restrict__ out,
    int N) {
  __shared__ unsigned long long codes[ROWS_PER_BLOCK];

  const int tid  = threadIdx.x;
  const int row0 = blockIdx.x * ROWS_PER_BLOCK;

  // ---- Phase 1: one lane per row builds the packed ancestor code ----
  if (tid < ROWS_PER_BLOCK) {
    int row = row0 + tid;
    unsigned long long code = 0;
    if (row < N) {
      int d  = depth[row];
      int dd = d < PE_K ? d : PE_K;
      int cur = row;
      for (int j = 0; j < dd; ++j) {
        int ci = child_idx[cur] & 7;
        code |= (unsigned long long)ci << (3 * j);
        cur = parent[cur];
      }
      code |= (unsigned long long)dd << 48;
    }
    codes[tid] = code;
  }
  __syncthreads();

  // ---- Phase 2: stream 128 rows x 32 float4, all constants hoisted ----
  const int c  = tid & 31;        // float4 chunk within row (constant)
  const int g  = tid >> 5;        // row-group 0..7 (constant)
  const int j  = c >> 1;          // 8-wide level slot (constant)
  const int sh = 3 * j;           // code shift (constant)
  const int r0 = 4 * c - 8 * j;   // compare window base: 0 or 4 (constant)

  float4* p = reinterpret_cast<float4*>(out) + ((long long)(row0 + g) * 32 + c);
  const int last_full_rl = N - row0;   // rows with rl < this are valid

  #pragma unroll
  for (int it = 0; it < ROWS_PER_BLOCK / 8; ++it) {
    int rl = it * 8 + g;
    unsigned long long code = codes[rl];
    int dd = (int)(code >> 48);
    int ci = (int)((code >> sh) & 7);
    ci = (j < dd) ? ci : 8;            // 8 = matches nothing -> zeros

    float4 v;
    v.x = (ci == r0 + 0) ? 1.f : 0.f;
    v.y = (ci == r0 + 1) ? 1.f : 0.f;
    v.z = (ci == r0 + 2) ? 1.f : 0.f;
    v.w = (ci == r0 + 3) ? 1.f : 0.f;

    if (rl < last_full_rl) *p = v;     // only the last block is ever partial
    p += 8 * 32;                       // advance 8 rows
  }
}

extern "C" void kernel_launch(void* const* d_in, const int* in_sizes, int n_in,
                              void* d_out, int out_size, void* d_ws, size_t ws_size,
                              hipStream_t stream) {
  const int* parent    = (const int*)d_in[0];
  const int* child_idx = (const int*)d_in[1];
  const int* depth     = (const int*)d_in[2];
  // d_in[3] = p_emb (unused), d_in[4] = n (=8), d_in[5] = k (=16)
  float* out = (float*)d_out;
  int N = in_sizes[0];

  int grid = (N + ROWS_PER_BLOCK - 1) / ROWS_PER_BLOCK;   // 1563 @ N=200k
  PositionalEmbedding_kernel<<<grid, 256, 0, stream>>>(parent, child_idx, depth, out, N);
}